// Round 12
// baseline (69.675 us; speedup 1.0000x reference)
//
#include <hip/hip_runtime.h>
#include <stdint.h>

#define LMAX 8
#define KCH 32
#define NC  64
#define TT  2048
#define LN2D 0.6931471805599453
#define NEGE (-(1<<28))
#define VG 4

__device__ __forceinline__ int fexp(float m) { return ((__float_as_int(m) >> 23) & 0xFF) - 127; }
__device__ __forceinline__ int fexpbits(float m) { return (__float_as_int(m) >> 23) & 0xFF; }
__device__ __forceinline__ float p2(int e) { return __int_as_float((e + 127) << 23); }
__device__ __forceinline__ float p2c(int e) { return (e < -126) ? 0.f : p2(e); }

// K1: match -> partial M (verbatim R11, proven).
__global__ __launch_bounds__(256) void k_front(const int* __restrict__ seq,
        const int* __restrict__ pieces, const int* __restrict__ plens,
        const float* __restrict__ logp, float* __restrict__ Mpart, int T, int V) {
  __shared__ int sSeq[40];
  __shared__ unsigned long long sw[32];
  __shared__ float sM[32][8];
  const int tid = threadIdx.x;
  const int g = blockIdx.x;
  const int c = blockIdx.y;
  const int base = c * KCH;

  if (tid < 40) {
    int pos = base + tid;
    sSeq[tid] = (pos < T) ? (seq[pos] & 0xFF) : 0xFF;
  }
  ((float*)sM)[tid] = 0.f;
  __syncthreads();
  if (tid < 32) {
    unsigned long long w = 0ull;
    #pragma unroll
    for (int l = 0; l < LMAX; ++l)
      w |= (unsigned long long)sSeq[tid + l] << (8 * l);
    sw[tid] = w;
  }
  __syncthreads();

  for (int r = 0; r < 8; ++r) {
    int v = (g * 8 + r) * 256 + tid;
    const int4* pr = (const int4*)(pieces + v * LMAX);
    int4 pa = pr[0], pb = pr[1];
    int len = plens[v];
    unsigned long long key = 0ull;
    if (0 < len) key |= (unsigned long long)(pa.x & 0xFF);
    if (1 < len) key |= (unsigned long long)(pa.y & 0xFF) << 8;
    if (2 < len) key |= (unsigned long long)(pa.z & 0xFF) << 16;
    if (3 < len) key |= (unsigned long long)(pa.w & 0xFF) << 24;
    if (4 < len) key |= (unsigned long long)(pb.x & 0xFF) << 32;
    if (5 < len) key |= (unsigned long long)(pb.y & 0xFF) << 40;
    if (6 < len) key |= (unsigned long long)(pb.z & 0xFF) << 48;
    if (7 < len) key |= (unsigned long long)(pb.w & 0xFF) << 56;
    unsigned long long mask = (len >= 8) ? ~0ull : ((1ull << (8 * len)) - 1ull);
    float prob = -1.f;
    #pragma unroll
    for (int t = 0; t < 32; ++t) {
      if (((sw[t] ^ key) & mask) == 0ull) {
        if (prob < 0.f) prob = expf(logp[v]);
        atomicAdd(&sM[t][len - 1], prob);
      }
    }
  }
  __syncthreads();
  if (tid < 64) ((float4*)Mpart)[((size_t)g * NC + c) * 64 + tid] = ((float4*)sM)[tid];
}

// K2: per-chunk block: sum partials -> LDS + M; 16 lanes compute both chunk
// transfer matrices with register-batched rows (no serial global chain).
__global__ __launch_bounds__(64, 1) void k_mat(const float* __restrict__ Mpart,
        float* __restrict__ M, float* __restrict__ Wt, int* __restrict__ EWc) {
  __shared__ float sM[32][8];
  const int tid = threadIdx.x;
  const int c = blockIdx.x;
  {
    const float4* Mp = (const float4*)Mpart;
    float4 a  = Mp[((size_t)(0 * NC + c)) * 64 + tid];
    float4 b  = Mp[((size_t)(1 * NC + c)) * 64 + tid];
    float4 cc = Mp[((size_t)(2 * NC + c)) * 64 + tid];
    float4 d  = Mp[((size_t)(3 * NC + c)) * 64 + tid];
    float4 s;
    s.x = (a.x + b.x) + (cc.x + d.x);
    s.y = (a.y + b.y) + (cc.y + d.y);
    s.z = (a.z + b.z) + (cc.z + d.z);
    s.w = (a.w + b.w) + (cc.w + d.w);
    ((float4*)sM)[tid] = s;
    ((float4*)M)[(size_t)c * 64 + tid] = s;
  }
  __syncthreads();

  if (tid < 16) {
    const int dir = tid >> 3, b = tid & 7;
    float v[8];
    #pragma unroll
    for (int i = 0; i < 8; ++i) v[i] = (i == b) ? 1.f : 0.f;
    int ec = 0;
    float4 buf[32];
    if (dir == 0) {
      #pragma unroll
      for (int half = 0; half < 2; ++half) {
        #pragma unroll
        for (int i = 0; i < 16; ++i) {
          buf[2 * i]     = *(const float4*)&sM[half * 16 + i][0];
          buf[2 * i + 1] = *(const float4*)&sM[half * 16 + i][4];
        }
        #pragma unroll
        for (int i = 0; i < 16; ++i) {
          const int kk = half * 16 + i;
          float4 c0 = buf[2 * i], c1 = buf[2 * i + 1];
          float a_ = v[kk & 7];
          v[(kk + 1) & 7] = fmaf(a_, c0.x, v[(kk + 1) & 7]);
          v[(kk + 2) & 7] = fmaf(a_, c0.y, v[(kk + 2) & 7]);
          v[(kk + 3) & 7] = fmaf(a_, c0.z, v[(kk + 3) & 7]);
          v[(kk + 4) & 7] = fmaf(a_, c0.w, v[(kk + 4) & 7]);
          v[(kk + 5) & 7] = fmaf(a_, c1.x, v[(kk + 5) & 7]);
          v[(kk + 6) & 7] = fmaf(a_, c1.y, v[(kk + 6) & 7]);
          v[(kk + 7) & 7] = fmaf(a_, c1.z, v[(kk + 7) & 7]);
          v[kk & 7]       = a_ * c1.w;
          if ((kk & 3) == 3) {
            float mx = 0.f;
            #pragma unroll
            for (int q = 0; q < 8; ++q) mx = fmaxf(mx, v[q]);
            if (fexpbits(mx) != 0) {
              int e = fexp(mx); float sc = p2(-e);
              #pragma unroll
              for (int q = 0; q < 8; ++q) v[q] *= sc;
              ec += e;
            }
          }
        }
      }
    } else {
      #pragma unroll
      for (int half = 0; half < 2; ++half) {
        #pragma unroll
        for (int i = 0; i < 16; ++i) {
          int row = 31 - (half * 16 + i);
          buf[2 * i]     = *(const float4*)&sM[row][0];
          buf[2 * i + 1] = *(const float4*)&sM[row][4];
        }
        #pragma unroll
        for (int i = 0; i < 16; ++i) {
          const int kk = half * 16 + i;
          float4 c0 = buf[2 * i], c1 = buf[2 * i + 1];
          float nb =      c0.x * v[(8  - kk) & 7];
          nb = fmaf(c0.y, v[(9  - kk) & 7], nb);
          nb = fmaf(c0.z, v[(10 - kk) & 7], nb);
          nb = fmaf(c0.w, v[(11 - kk) & 7], nb);
          nb = fmaf(c1.x, v[(12 - kk) & 7], nb);
          nb = fmaf(c1.y, v[(13 - kk) & 7], nb);
          nb = fmaf(c1.z, v[(14 - kk) & 7], nb);
          nb = fmaf(c1.w, v[(15 - kk) & 7], nb);
          v[(7 - kk) & 7] = nb;
          if ((kk & 3) == 3) {
            float mx = 0.f;
            #pragma unroll
            for (int q = 0; q < 8; ++q) mx = fmaxf(mx, v[q]);
            if (fexpbits(mx) != 0) {
              int e = fexp(mx); float sc = p2(-e);
              #pragma unroll
              for (int q = 0; q < 8; ++q) v[q] *= sc;
              ec += e;
            }
          }
        }
      }
    }
    float mx = 0.f;
    #pragma unroll
    for (int i = 0; i < 8; ++i) mx = fmaxf(mx, v[i]);
    int lt = dir * 64 + (dir ? 63 - c : c);
    float* wp = Wt + lt * 64;
    if (fexpbits(mx) == 0) {
      #pragma unroll
      for (int i = 0; i < 8; ++i) wp[b * 8 + i] = 0.f;
      EWc[lt * 8 + b] = NEGE;
    } else {
      int e = fexp(mx); float sc = p2(-e);
      #pragma unroll
      for (int i = 0; i < 8; ++i) wp[b * 8 + i] = v[i] * sc;
      EWc[lt * 8 + b] = ec + e;
    }
  }
}

// K3: combine levels A/B/C (verbatim), Cs/Eacc to global. 1 block x 128.
__global__ __launch_bounds__(128, 1) void k_comb(const float* __restrict__ Wt,
        const int* __restrict__ EWc, float* __restrict__ Pm,
        float* __restrict__ Cs, int* __restrict__ Eacc) {
  __shared__ float sWt[128][68];
  __shared__ int   sEW[128 * 8];
  __shared__ int   sEP[128 * 8];
  __shared__ float Gm[16 * 69];
  __shared__ float Sg[16 * 9];
  __shared__ int   EGs[16 * 8];
  __shared__ int   EsB[16];
  const int tid = threadIdx.x;

  for (int i = tid; i < 128 * 16; i += 128) {
    int task = i >> 4, q = i & 15;
    float4 v4 = ((const float4*)Wt)[i];
    *(float4*)&sWt[task][q * 4] = v4;
  }
  for (int i = tid; i < 1024; i += 128) sEW[i] = EWc[i];
  __syncthreads();

  {
    const int dir = tid >> 6, w = (tid >> 3) & 7, b = tid & 7;
    float v[8];
    #pragma unroll
    for (int i = 0; i < 8; ++i) v[i] = (i == b) ? 1.f : 0.f;
    int ec = 0;
    for (int c = 0; c < 8; ++c) {
      int lc = w * 8 + c, lt = dir * 64 + lc;
      float* pp = Pm + lt * 64 + b * 8;
      #pragma unroll
      for (int i = 0; i < 8; ++i) pp[i] = v[i];
      sEP[lt * 8 + b] = ec;
      const float* wp = &sWt[lt][0];
      int ew[8];
      #pragma unroll
      for (int j = 0; j < 8; ++j) ew[j] = sEW[lt * 8 + j];
      int emax = ew[0];
      #pragma unroll
      for (int j = 1; j < 8; ++j) emax = max(emax, ew[j]);
      float nv[8] = {0, 0, 0, 0, 0, 0, 0, 0};
      #pragma unroll
      for (int j = 0; j < 8; ++j) {
        float tj = v[j] * p2c(ew[j] - emax + 64);
        float4 ca = *(const float4*)(wp + j * 8);
        float4 cb = *(const float4*)(wp + j * 8 + 4);
        nv[0] = fmaf(tj, ca.x, nv[0]); nv[1] = fmaf(tj, ca.y, nv[1]);
        nv[2] = fmaf(tj, ca.z, nv[2]); nv[3] = fmaf(tj, ca.w, nv[3]);
        nv[4] = fmaf(tj, cb.x, nv[4]); nv[5] = fmaf(tj, cb.y, nv[5]);
        nv[6] = fmaf(tj, cb.z, nv[6]); nv[7] = fmaf(tj, cb.w, nv[7]);
      }
      float mx = 0.f;
      #pragma unroll
      for (int i = 0; i < 8; ++i) mx = fmaxf(mx, nv[i]);
      if (fexpbits(mx) == 0) {
        #pragma unroll
        for (int i = 0; i < 8; ++i) v[i] = 0.f;
        ec = NEGE;
      } else {
        int e = fexp(mx); float sc = p2(-e);
        #pragma unroll
        for (int i = 0; i < 8; ++i) v[i] = nv[i] * sc;
        ec = ec + emax + e - 64;
      }
    }
    float* gp = Gm + (dir * 8 + w) * 69 + b * 8;
    #pragma unroll
    for (int i = 0; i < 8; ++i) gp[i] = v[i];
    EGs[(dir * 8 + w) * 8 + b] = ec;
  }
  __syncthreads();

  if (tid < 8 || (tid >= 64 && tid < 72)) {
    const int dir = (tid >= 64) ? 1 : 0, j = tid & 7;
    float s[8];
    #pragma unroll
    for (int i = 0; i < 8; ++i) s[i] = (i == 0) ? 1.f : 0.f;
    int Es = 0;
    for (int w = 0; w < 8; ++w) {
      float sj = s[0];
      #pragma unroll
      for (int i = 1; i < 8; ++i) if (j == i) sj = s[i];
      Sg[(dir * 8 + w) * 9 + j] = sj;
      if (j == 0) EsB[dir * 8 + w] = Es;
      int eg[8];
      #pragma unroll
      for (int i = 0; i < 8; ++i) eg[i] = EGs[(dir * 8 + w) * 8 + i];
      int egmax = eg[0];
      #pragma unroll
      for (int i = 1; i < 8; ++i) egmax = max(egmax, eg[i]);
      int egj = eg[0];
      #pragma unroll
      for (int i = 1; i < 8; ++i) if (j == i) egj = eg[i];
      float tb = sj * p2c(egj - egmax + 64);
      const float* gp = Gm + (dir * 8 + w) * 69 + j * 8;
      float p[8];
      #pragma unroll
      for (int i = 0; i < 8; ++i) p[i] = gp[i] * tb;
      #pragma unroll
      for (int m = 1; m <= 4; m <<= 1)
        #pragma unroll
        for (int i = 0; i < 8; ++i) p[i] += __shfl_xor(p[i], m);
      float mx = 0.f;
      #pragma unroll
      for (int i = 0; i < 8; ++i) mx = fmaxf(mx, p[i]);
      int e = fexp(mx); float sc = p2(-e);
      #pragma unroll
      for (int i = 0; i < 8; ++i) s[i] = p[i] * sc;
      Es += egmax + e - 64;
    }
  }
  __syncthreads();

  {
    const int dir = tid >> 6, lc = tid & 63, w = lc >> 3;
    float sg[8];
    #pragma unroll
    for (int b = 0; b < 8; ++b) sg[b] = Sg[(dir * 8 + w) * 9 + b];
    int Es = EsB[dir * 8 + w];
    int ep[8];
    #pragma unroll
    for (int b = 0; b < 8; ++b) ep[b] = sEP[(dir * 64 + lc) * 8 + b];
    int epmax = ep[0];
    #pragma unroll
    for (int b = 1; b < 8; ++b) epmax = max(epmax, ep[b]);
    float cs[8] = {0, 0, 0, 0, 0, 0, 0, 0};
    #pragma unroll
    for (int b = 0; b < 8; ++b) {
      float coef = sg[b] * p2c(ep[b] - epmax + 64);
      const float* pp = Pm + (dir * 64 + lc) * 64 + b * 8;
      float4 ca = *(const float4*)pp;
      float4 cb = *(const float4*)(pp + 4);
      cs[0] = fmaf(coef, ca.x, cs[0]); cs[1] = fmaf(coef, ca.y, cs[1]);
      cs[2] = fmaf(coef, ca.z, cs[2]); cs[3] = fmaf(coef, ca.w, cs[3]);
      cs[4] = fmaf(coef, cb.x, cs[4]); cs[5] = fmaf(coef, cb.y, cs[5]);
      cs[6] = fmaf(coef, cb.z, cs[6]); cs[7] = fmaf(coef, cb.w, cs[7]);
    }
    float mx = 0.f;
    #pragma unroll
    for (int i = 0; i < 8; ++i) mx = fmaxf(mx, cs[i]);
    int phys = dir ? (63 - lc) : lc;
    float* cp = Cs + (dir * 64 + phys) * 8;
    if (fexpbits(mx) == 0) {
      #pragma unroll
      for (int i = 0; i < 8; ++i) cp[i] = 0.f;
      Eacc[dir * 64 + phys] = NEGE;
    } else {
      int e = fexp(mx); float sc = p2(-e);
      #pragma unroll
      for (int i = 0; i < 8; ++i) cp[i] = cs[i] * sc;
      Eacc[dir * 64 + phys] = Es + epmax + e - 64;
    }
  }
}

// K4: fp64 replay + fused log, register-batched M rows. <<<2,64>>> dir=blockIdx.
__global__ __launch_bounds__(64, 1) void k_rep(const float* __restrict__ M,
        const float* __restrict__ Cs, const int* __restrict__ Eacc,
        float* __restrict__ aL, float* __restrict__ bL) {
  const int dir = blockIdx.x;
  const int c = threadIdx.x;
  const int base = c * KCH;
  const float4* Mv = (const float4*)M;
  const float* cp = Cs + (dir * 64 + c) * 8;
  double st[8];
  #pragma unroll
  for (int i = 0; i < 8; ++i) st[i] = (double)cp[i];
  const double eacc = (double)Eacc[dir * 64 + c];
  float4 buf[32];
  if (dir == 0) {
    if (c == 0) aL[0] = 0.f;
    #pragma unroll
    for (int half = 0; half < 2; ++half) {
      #pragma unroll
      for (int i = 0; i < 16; ++i) {
        int row = base + half * 16 + i;
        buf[2 * i]     = Mv[row * 2];
        buf[2 * i + 1] = Mv[row * 2 + 1];
      }
      #pragma unroll
      for (int i = 0; i < 16; ++i) {
        const int kk = half * 16 + i;
        float4 c0 = buf[2 * i], c1 = buf[2 * i + 1];
        double a_ = st[kk & 7];
        st[(kk + 1) & 7] = fma(a_, (double)c0.x, st[(kk + 1) & 7]);
        st[(kk + 2) & 7] = fma(a_, (double)c0.y, st[(kk + 2) & 7]);
        st[(kk + 3) & 7] = fma(a_, (double)c0.z, st[(kk + 3) & 7]);
        st[(kk + 4) & 7] = fma(a_, (double)c0.w, st[(kk + 4) & 7]);
        st[(kk + 5) & 7] = fma(a_, (double)c1.x, st[(kk + 5) & 7]);
        st[(kk + 6) & 7] = fma(a_, (double)c1.y, st[(kk + 6) & 7]);
        st[(kk + 7) & 7] = fma(a_, (double)c1.z, st[(kk + 7) & 7]);
        st[kk & 7]       = a_ * (double)c1.w;
        double val = st[(kk + 1) & 7];
        long long bits = __double_as_longlong(val);
        int e2 = (int)((bits >> 52) & 0x7ff) - 1023;
        double mant = __longlong_as_double((bits & 0xFFFFFFFFFFFFFLL) | 0x3FF0000000000000LL);
        float lg = log2f((float)mant);
        aL[base + kk + 1] = (float)(((double)e2 + eacc + (double)lg) * LN2D);
      }
    }
  } else {
    if (c == 0) bL[TT] = 0.f;
    #pragma unroll
    for (int half = 0; half < 2; ++half) {
      #pragma unroll
      for (int i = 0; i < 16; ++i) {
        int row = base + 31 - (half * 16 + i);
        buf[2 * i]     = Mv[row * 2];
        buf[2 * i + 1] = Mv[row * 2 + 1];
      }
      #pragma unroll
      for (int i = 0; i < 16; ++i) {
        const int kk = half * 16 + i;
        const int t = base + 31 - kk;
        float4 c0 = buf[2 * i], c1 = buf[2 * i + 1];
        double nb =            (double)c0.x * st[(8  - kk) & 7];
        nb = fma((double)c0.y, st[(9  - kk) & 7], nb);
        nb = fma((double)c0.z, st[(10 - kk) & 7], nb);
        nb = fma((double)c0.w, st[(11 - kk) & 7], nb);
        nb = fma((double)c1.x, st[(12 - kk) & 7], nb);
        nb = fma((double)c1.y, st[(13 - kk) & 7], nb);
        nb = fma((double)c1.z, st[(14 - kk) & 7], nb);
        nb = fma((double)c1.w, st[(15 - kk) & 7], nb);
        st[(7 - kk) & 7] = nb;
        long long bits = __double_as_longlong(nb);
        int e2 = (int)((bits >> 52) & 0x7ff) - 1023;
        double mant = __longlong_as_double((bits & 0xFFFFFFFFFFFFFLL) | 0x3FF0000000000000LL);
        float lg = log2f((float)mant);
        bL[t] = (float)(((double)e2 + eacc + (double)lg) * LN2D);
      }
    }
  }
}

// K5: dense output (verbatim R11).
__global__ __launch_bounds__(256) void k_out(const int* __restrict__ seq,
        const int* __restrict__ pieces, const int* __restrict__ plens,
        const float* __restrict__ logp, const float* __restrict__ aL,
        const float* __restrict__ bL, float* __restrict__ out, int T, int V) {
  __shared__ int sSeq[40];
  __shared__ unsigned long long sw[32];
  const int tid = threadIdx.x;
  const int t0 = blockIdx.y * 32;
  const int v0 = blockIdx.x * 1024 + tid * 4;
  if (tid < 40) {
    int pos = t0 + tid;
    sSeq[tid] = (pos < T) ? (seq[pos] & 0xFF) : 0xFF;
  }
  __syncthreads();
  if (tid < 32) {
    unsigned long long w = 0ull;
    #pragma unroll
    for (int l = 0; l < LMAX; ++l)
      w |= (unsigned long long)sSeq[tid + l] << (8 * l);
    sw[tid] = w;
  }
  __syncthreads();

  float norm = aL[T];
  unsigned long long key[4], mask[4];
  int len[4];
  float lpb[4];
  #pragma unroll
  for (int j = 0; j < 4; ++j) {
    int v = v0 + j;
    const int4* pr = (const int4*)(pieces + v * LMAX);
    int4 pa = pr[0], pb = pr[1];
    int ln = plens[v];
    unsigned long long k_ = 0ull;
    if (0 < ln) k_ |= (unsigned long long)(pa.x & 0xFF);
    if (1 < ln) k_ |= (unsigned long long)(pa.y & 0xFF) << 8;
    if (2 < ln) k_ |= (unsigned long long)(pa.z & 0xFF) << 16;
    if (3 < ln) k_ |= (unsigned long long)(pa.w & 0xFF) << 24;
    if (4 < ln) k_ |= (unsigned long long)(pb.x & 0xFF) << 32;
    if (5 < ln) k_ |= (unsigned long long)(pb.y & 0xFF) << 40;
    if (6 < ln) k_ |= (unsigned long long)(pb.z & 0xFF) << 48;
    if (7 < ln) k_ |= (unsigned long long)(pb.w & 0xFF) << 56;
    key[j] = k_;
    mask[j] = (ln >= 8) ? ~0ull : ((1ull << (8 * ln)) - 1ull);
    len[j] = ln;
    lpb[j] = logp[v] - norm;
  }

  for (int tt = 0; tt < 32; ++tt) {
    int t = t0 + tt;
    unsigned long long w = sw[tt];
    float al = aL[t];
    float4 o = make_float4(0.f, 0.f, 0.f, 0.f);
    if (((w ^ key[0]) & mask[0]) == 0ull) o.x = __expf(al + lpb[0] + bL[t + len[0]]);
    if (((w ^ key[1]) & mask[1]) == 0ull) o.y = __expf(al + lpb[1] + bL[t + len[1]]);
    if (((w ^ key[2]) & mask[2]) == 0ull) o.z = __expf(al + lpb[2] + bL[t + len[2]]);
    if (((w ^ key[3]) & mask[3]) == 0ull) o.w = __expf(al + lpb[3] + bL[t + len[3]]);
    *(float4*)&out[(size_t)t * V + v0] = o;
  }
}

extern "C" void kernel_launch(void* const* d_in, const int* in_sizes, int n_in,
                              void* d_out, int out_size, void* d_ws, size_t ws_size,
                              hipStream_t stream) {
  const int* seq    = (const int*)d_in[0];
  const int* pieces = (const int*)d_in[1];
  const int* plens  = (const int*)d_in[2];
  const float* logp = (const float*)d_in[3];
  float* out = (float*)d_out;
  const int T = in_sizes[0];
  const int V = in_sizes[2];

  char* p = (char*)d_ws;
  float* Mpart = (float*)p;  p += (size_t)VG * NC * KCH * LMAX * 4;  // 256 KB
  float* M = (float*)p;      p += (size_t)TT * LMAX * 4;             // 64 KB
  float* Wt = (float*)p;     p += (size_t)128 * 64 * 4;              // 32 KB
  int* EWc = (int*)p;        p += (size_t)128 * 8 * 4;               // 4 KB
  float* Pm = (float*)p;     p += (size_t)128 * 64 * 4;              // 32 KB
  float* Cs = (float*)p;     p += (size_t)128 * 8 * 4;               // 4 KB
  int* Eacc = (int*)p;       p += 512;
  float* aL = (float*)p;     p += 8208;
  float* bL = (float*)p;     p += 8208;

  dim3 g1(VG, NC);
  k_front<<<g1, 256, 0, stream>>>(seq, pieces, plens, logp, Mpart, T, V);
  k_mat<<<NC, 64, 0, stream>>>(Mpart, M, Wt, EWc);
  k_comb<<<1, 128, 0, stream>>>(Wt, EWc, Pm, Cs, Eacc);
  k_rep<<<2, 64, 0, stream>>>(M, Cs, Eacc, aL, bL);
  dim3 g3(V / 1024, T / 32);
  k_out<<<g3, 256, 0, stream>>>(seq, pieces, plens, logp, aL, bL, out, T, V);
}

// Round 13
// 58.636 us; speedup vs baseline: 1.1883x; 1.1883x over previous
//
#include <hip/hip_runtime.h>
#include <stdint.h>

#define LMAX 8
#define KCH 32
#define NC  64
#define TT  2048
#define LN2D 0.6931471805599453
#define NEGE (-(1<<28))

struct __align__(16) PK { unsigned long long key; float logp; int len; };

__device__ __forceinline__ int fexp(float m) { return ((__float_as_int(m) >> 23) & 0xFF) - 127; }
__device__ __forceinline__ int fexpbits(float m) { return (__float_as_int(m) >> 23) & 0xFF; }
__device__ __forceinline__ float p2(int e) { return __int_as_float((e + 127) << 23); }
__device__ __forceinline__ float p2c(int e) { return (e < -126) ? 0.f : p2(e); }

// K1: pack pieces into 64-bit keys, pack sequence windows, zero M. (R7 verbatim)
__global__ void k_prep(const int* __restrict__ seq, const int* __restrict__ pieces,
                       const int* __restrict__ plens, const float* __restrict__ logp,
                       PK* __restrict__ pk, unsigned long long* __restrict__ w64,
                       float* __restrict__ M, int T, int V) {
  int idx = blockIdx.x * blockDim.x + threadIdx.x;
  if (idx < V) {
    const int* pr = pieces + idx * LMAX;
    int len = plens[idx];
    unsigned long long key = 0ull;
    #pragma unroll
    for (int l = 0; l < LMAX; ++l) {
      unsigned long long b = (unsigned long long)(pr[l] & 0xFF);
      if (l < len) key |= b << (8 * l);
    }
    PK o; o.key = key; o.logp = logp[idx]; o.len = len;
    pk[idx] = o;
  } else if (idx < V + T) {
    int t = idx - V;
    unsigned long long w = 0ull;
    #pragma unroll
    for (int l = 0; l < LMAX; ++l) {
      int pos = t + l;
      unsigned long long b = (pos < T) ? (unsigned long long)(seq[pos] & 0xFF) : 0xFFull;
      w |= b << (8 * l);
    }
    w64[t] = w;
  } else if (idx < V + T + T * LMAX) {
    M[idx - V - T] = 0.f;
  }
}

// K2: M[t][len-1] += p_v for every matching (t,v). (R7 verbatim)
__global__ void k_match(const PK* __restrict__ pk, const unsigned long long* __restrict__ w64,
                        float* __restrict__ M, int T, int V, int tPer) {
  int v = blockIdx.x * blockDim.x + threadIdx.x;
  PK p = pk[v];
  unsigned long long mask = (p.len >= 8) ? ~0ull : ((1ull << (8 * p.len)) - 1ull);
  unsigned long long key = p.key;
  int t0 = blockIdx.y * tPer;
  float prob = -1.f;
  for (int t = t0; t < t0 + tPer; ++t) {
    unsigned long long w = w64[t];
    if (((w ^ key) & mask) == 0ull) {
      if (prob < 0.f) prob = expf(p.logp);
      atomicAdd(&M[t * LMAX + (p.len - 1)], prob);
    }
  }
}

// K3a: chunk transfer-matrix columns. 16 blocks x 64 thr. Rows batch-loaded
// 16-at-a-time into registers (independent loads) -> no serial load chain.
__global__ __launch_bounds__(64, 1) void k_chunks(const float* __restrict__ M,
        float* __restrict__ Wt, int* __restrict__ EWc) {
  int gtid = blockIdx.x * 64 + threadIdx.x;    // 0..1023
  int task = gtid >> 3, b = gtid & 7;
  int dir = task >> 6, c = task & 63;
  int base = c * KCH;
  const float4* Mv = (const float4*)M;
  float v[8];
  #pragma unroll
  for (int i = 0; i < 8; ++i) v[i] = (i == b) ? 1.f : 0.f;
  int ec = 0;
  float4 buf[32];
  if (dir == 0) {          // alpha push-form
    #pragma unroll
    for (int half = 0; half < 2; ++half) {
      #pragma unroll
      for (int i = 0; i < 16; ++i) {
        int row = base + half * 16 + i;
        buf[2 * i]     = Mv[row * 2];
        buf[2 * i + 1] = Mv[row * 2 + 1];
      }
      #pragma unroll
      for (int i = 0; i < 16; ++i) {
        const int kk = half * 16 + i;
        float4 c0 = buf[2 * i], c1 = buf[2 * i + 1];
        float a_ = v[kk & 7];
        v[(kk + 1) & 7] = fmaf(a_, c0.x, v[(kk + 1) & 7]);
        v[(kk + 2) & 7] = fmaf(a_, c0.y, v[(kk + 2) & 7]);
        v[(kk + 3) & 7] = fmaf(a_, c0.z, v[(kk + 3) & 7]);
        v[(kk + 4) & 7] = fmaf(a_, c0.w, v[(kk + 4) & 7]);
        v[(kk + 5) & 7] = fmaf(a_, c1.x, v[(kk + 5) & 7]);
        v[(kk + 6) & 7] = fmaf(a_, c1.y, v[(kk + 6) & 7]);
        v[(kk + 7) & 7] = fmaf(a_, c1.z, v[(kk + 7) & 7]);
        v[kk & 7]       = a_ * c1.w;
        if ((kk & 3) == 3) {
          float mx = 0.f;
          #pragma unroll
          for (int q = 0; q < 8; ++q) mx = fmaxf(mx, v[q]);
          if (fexpbits(mx) != 0) {
            int e = fexp(mx); float sc = p2(-e);
            #pragma unroll
            for (int q = 0; q < 8; ++q) v[q] *= sc;
            ec += e;
          }
        }
      }
    }
  } else {                 // beta window-form
    #pragma unroll
    for (int half = 0; half < 2; ++half) {
      #pragma unroll
      for (int i = 0; i < 16; ++i) {
        int row = base + 31 - (half * 16 + i);
        buf[2 * i]     = Mv[row * 2];
        buf[2 * i + 1] = Mv[row * 2 + 1];
      }
      #pragma unroll
      for (int i = 0; i < 16; ++i) {
        const int kk = half * 16 + i;
        float4 c0 = buf[2 * i], c1 = buf[2 * i + 1];
        float nb =      c0.x * v[(8  - kk) & 7];
        nb = fmaf(c0.y, v[(9  - kk) & 7], nb);
        nb = fmaf(c0.z, v[(10 - kk) & 7], nb);
        nb = fmaf(c0.w, v[(11 - kk) & 7], nb);
        nb = fmaf(c1.x, v[(12 - kk) & 7], nb);
        nb = fmaf(c1.y, v[(13 - kk) & 7], nb);
        nb = fmaf(c1.z, v[(14 - kk) & 7], nb);
        nb = fmaf(c1.w, v[(15 - kk) & 7], nb);
        v[(7 - kk) & 7] = nb;
        if ((kk & 3) == 3) {
          float mx = 0.f;
          #pragma unroll
          for (int q = 0; q < 8; ++q) mx = fmaxf(mx, v[q]);
          if (fexpbits(mx) != 0) {
            int e = fexp(mx); float sc = p2(-e);
            #pragma unroll
            for (int q = 0; q < 8; ++q) v[q] *= sc;
            ec += e;
          }
        }
      }
    }
  }
  float mx = 0.f;
  #pragma unroll
  for (int i = 0; i < 8; ++i) mx = fmaxf(mx, v[i]);
  int ltask = dir * 64 + (dir ? 63 - c : c);
  float* wp = Wt + ltask * 64;
  if (fexpbits(mx) == 0) {
    #pragma unroll
    for (int i = 0; i < 8; ++i) wp[b * 8 + i] = 0.f;
    EWc[ltask * 8 + b] = NEGE;
  } else {
    int e = fexp(mx); float sc = p2(-e);
    #pragma unroll
    for (int i = 0; i < 8; ++i) wp[b * 8 + i] = v[i] * sc;
    EWc[ltask * 8 + b] = ec + e;
  }
}

// K3b: combine (levels A/B/C) + fp64 replay + log, one 128-thread block.
// Verbatim R7 except the replay's M rows are batch-loaded into registers.
__global__ __launch_bounds__(128, 1) void k_fin(const float* __restrict__ M,
        const float* __restrict__ Wt, const int* __restrict__ EWc,
        float* __restrict__ Pm, float* __restrict__ aL, float* __restrict__ bL) {
  __shared__ float sWt[128][68];
  __shared__ int   sEW[128 * 8];
  __shared__ int   sEP[128 * 8];
  __shared__ float Gm[16 * 69];
  __shared__ float Sg[16 * 9];
  __shared__ int   EGs[16 * 8];
  __shared__ int   EsB[16];
  __shared__ float sCs[128 * 8];
  __shared__ int   sEacc[128];
  const int tid = threadIdx.x;
  const float4* Mv = (const float4*)M;

  for (int i = tid; i < 128 * 16; i += 128) {
    int task = i >> 4, q = i & 15;
    float4 v4 = ((const float4*)Wt)[i];
    *(float4*)&sWt[task][q * 4] = v4;
  }
  for (int i = tid; i < 1024; i += 128) sEW[i] = EWc[i];
  __syncthreads();

  // level A
  {
    const int dir = tid >> 6, w = (tid >> 3) & 7, b = tid & 7;
    float v[8];
    #pragma unroll
    for (int i = 0; i < 8; ++i) v[i] = (i == b) ? 1.f : 0.f;
    int ec = 0;
    for (int c = 0; c < 8; ++c) {
      int lc = w * 8 + c, lt = dir * 64 + lc;
      float* pp = Pm + lt * 64 + b * 8;
      #pragma unroll
      for (int i = 0; i < 8; ++i) pp[i] = v[i];
      sEP[lt * 8 + b] = ec;
      const float* wp = &sWt[lt][0];
      int ew[8];
      #pragma unroll
      for (int j = 0; j < 8; ++j) ew[j] = sEW[lt * 8 + j];
      int emax = ew[0];
      #pragma unroll
      for (int j = 1; j < 8; ++j) emax = max(emax, ew[j]);
      float nv[8] = {0, 0, 0, 0, 0, 0, 0, 0};
      #pragma unroll
      for (int j = 0; j < 8; ++j) {
        float tj = v[j] * p2c(ew[j] - emax + 64);
        float4 ca = *(const float4*)(wp + j * 8);
        float4 cb = *(const float4*)(wp + j * 8 + 4);
        nv[0] = fmaf(tj, ca.x, nv[0]); nv[1] = fmaf(tj, ca.y, nv[1]);
        nv[2] = fmaf(tj, ca.z, nv[2]); nv[3] = fmaf(tj, ca.w, nv[3]);
        nv[4] = fmaf(tj, cb.x, nv[4]); nv[5] = fmaf(tj, cb.y, nv[5]);
        nv[6] = fmaf(tj, cb.z, nv[6]); nv[7] = fmaf(tj, cb.w, nv[7]);
      }
      float mx = 0.f;
      #pragma unroll
      for (int i = 0; i < 8; ++i) mx = fmaxf(mx, nv[i]);
      if (fexpbits(mx) == 0) {
        #pragma unroll
        for (int i = 0; i < 8; ++i) v[i] = 0.f;
        ec = NEGE;
      } else {
        int e = fexp(mx); float sc = p2(-e);
        #pragma unroll
        for (int i = 0; i < 8; ++i) v[i] = nv[i] * sc;
        ec = ec + emax + e - 64;
      }
    }
    float* gp = Gm + (dir * 8 + w) * 69 + b * 8;
    #pragma unroll
    for (int i = 0; i < 8; ++i) gp[i] = v[i];
    EGs[(dir * 8 + w) * 8 + b] = ec;
  }
  __syncthreads();

  // level B
  if (tid < 8 || (tid >= 64 && tid < 72)) {
    const int dir = (tid >= 64) ? 1 : 0, j = tid & 7;
    float s[8];
    #pragma unroll
    for (int i = 0; i < 8; ++i) s[i] = (i == 0) ? 1.f : 0.f;
    int Es = 0;
    for (int w = 0; w < 8; ++w) {
      float sj = s[0];
      #pragma unroll
      for (int i = 1; i < 8; ++i) if (j == i) sj = s[i];
      Sg[(dir * 8 + w) * 9 + j] = sj;
      if (j == 0) EsB[dir * 8 + w] = Es;
      int eg[8];
      #pragma unroll
      for (int i = 0; i < 8; ++i) eg[i] = EGs[(dir * 8 + w) * 8 + i];
      int egmax = eg[0];
      #pragma unroll
      for (int i = 1; i < 8; ++i) egmax = max(egmax, eg[i]);
      int egj = eg[0];
      #pragma unroll
      for (int i = 1; i < 8; ++i) if (j == i) egj = eg[i];
      float tb = sj * p2c(egj - egmax + 64);
      const float* gp = Gm + (dir * 8 + w) * 69 + j * 8;
      float p[8];
      #pragma unroll
      for (int i = 0; i < 8; ++i) p[i] = gp[i] * tb;
      #pragma unroll
      for (int m = 1; m <= 4; m <<= 1)
        #pragma unroll
        for (int i = 0; i < 8; ++i) p[i] += __shfl_xor(p[i], m);
      float mx = 0.f;
      #pragma unroll
      for (int i = 0; i < 8; ++i) mx = fmaxf(mx, p[i]);
      int e = fexp(mx); float sc = p2(-e);
      #pragma unroll
      for (int i = 0; i < 8; ++i) s[i] = p[i] * sc;
      Es += egmax + e - 64;
    }
  }
  __syncthreads();

  // level C
  {
    const int dir = tid >> 6, lc = tid & 63, w = lc >> 3;
    float sg[8];
    #pragma unroll
    for (int b = 0; b < 8; ++b) sg[b] = Sg[(dir * 8 + w) * 9 + b];
    int Es = EsB[dir * 8 + w];
    int ep[8];
    #pragma unroll
    for (int b = 0; b < 8; ++b) ep[b] = sEP[(dir * 64 + lc) * 8 + b];
    int epmax = ep[0];
    #pragma unroll
    for (int b = 1; b < 8; ++b) epmax = max(epmax, ep[b]);
    float cs[8] = {0, 0, 0, 0, 0, 0, 0, 0};
    #pragma unroll
    for (int b = 0; b < 8; ++b) {
      float coef = sg[b] * p2c(ep[b] - epmax + 64);
      const float* pp = Pm + (dir * 64 + lc) * 64 + b * 8;
      float4 ca = *(const float4*)pp;
      float4 cb = *(const float4*)(pp + 4);
      cs[0] = fmaf(coef, ca.x, cs[0]); cs[1] = fmaf(coef, ca.y, cs[1]);
      cs[2] = fmaf(coef, ca.z, cs[2]); cs[3] = fmaf(coef, ca.w, cs[3]);
      cs[4] = fmaf(coef, cb.x, cs[4]); cs[5] = fmaf(coef, cb.y, cs[5]);
      cs[6] = fmaf(coef, cb.z, cs[6]); cs[7] = fmaf(coef, cb.w, cs[7]);
    }
    float mx = 0.f;
    #pragma unroll
    for (int i = 0; i < 8; ++i) mx = fmaxf(mx, cs[i]);
    int phys = dir ? (63 - lc) : lc;
    float* cp = &sCs[(dir * 64 + phys) * 8];
    if (fexpbits(mx) == 0) {
      #pragma unroll
      for (int i = 0; i < 8; ++i) cp[i] = 0.f;
      sEacc[dir * 64 + phys] = NEGE;
    } else {
      int e = fexp(mx); float sc = p2(-e);
      #pragma unroll
      for (int i = 0; i < 8; ++i) cp[i] = cs[i] * sc;
      sEacc[dir * 64 + phys] = Es + epmax + e - 64;
    }
  }
  __syncthreads();

  // fp64 replay + log, batch-16 register row loads (R12 k_rep body)
  {
    const int dir = tid >> 6;
    const int c = tid & 63;
    const int base = c * KCH;
    const float* cp = &sCs[(dir * 64 + c) * 8];
    double st[8];
    #pragma unroll
    for (int i = 0; i < 8; ++i) st[i] = (double)cp[i];
    const double eacc = (double)sEacc[dir * 64 + c];
    if (tid == 0) { aL[0] = 0.f; bL[TT] = 0.f; }
    float4 buf[32];
    if (dir == 0) {
      #pragma unroll
      for (int half = 0; half < 2; ++half) {
        #pragma unroll
        for (int i = 0; i < 16; ++i) {
          int row = base + half * 16 + i;
          buf[2 * i]     = Mv[row * 2];
          buf[2 * i + 1] = Mv[row * 2 + 1];
        }
        #pragma unroll
        for (int i = 0; i < 16; ++i) {
          const int kk = half * 16 + i;
          float4 c0 = buf[2 * i], c1 = buf[2 * i + 1];
          double a_ = st[kk & 7];
          st[(kk + 1) & 7] = fma(a_, (double)c0.x, st[(kk + 1) & 7]);
          st[(kk + 2) & 7] = fma(a_, (double)c0.y, st[(kk + 2) & 7]);
          st[(kk + 3) & 7] = fma(a_, (double)c0.z, st[(kk + 3) & 7]);
          st[(kk + 4) & 7] = fma(a_, (double)c0.w, st[(kk + 4) & 7]);
          st[(kk + 5) & 7] = fma(a_, (double)c1.x, st[(kk + 5) & 7]);
          st[(kk + 6) & 7] = fma(a_, (double)c1.y, st[(kk + 6) & 7]);
          st[(kk + 7) & 7] = fma(a_, (double)c1.z, st[(kk + 7) & 7]);
          st[kk & 7]       = a_ * (double)c1.w;
          double val = st[(kk + 1) & 7];
          long long bits = __double_as_longlong(val);
          int e2 = (int)((bits >> 52) & 0x7ff) - 1023;
          double mant = __longlong_as_double((bits & 0xFFFFFFFFFFFFFLL) | 0x3FF0000000000000LL);
          float lg = log2f((float)mant);
          aL[base + kk + 1] = (float)(((double)e2 + eacc + (double)lg) * LN2D);
        }
      }
    } else {
      #pragma unroll
      for (int half = 0; half < 2; ++half) {
        #pragma unroll
        for (int i = 0; i < 16; ++i) {
          int row = base + 31 - (half * 16 + i);
          buf[2 * i]     = Mv[row * 2];
          buf[2 * i + 1] = Mv[row * 2 + 1];
        }
        #pragma unroll
        for (int i = 0; i < 16; ++i) {
          const int kk = half * 16 + i;
          const int t = base + 31 - kk;
          float4 c0 = buf[2 * i], c1 = buf[2 * i + 1];
          double nb =            (double)c0.x * st[(8  - kk) & 7];
          nb = fma((double)c0.y, st[(9  - kk) & 7], nb);
          nb = fma((double)c0.z, st[(10 - kk) & 7], nb);
          nb = fma((double)c0.w, st[(11 - kk) & 7], nb);
          nb = fma((double)c1.x, st[(12 - kk) & 7], nb);
          nb = fma((double)c1.y, st[(13 - kk) & 7], nb);
          nb = fma((double)c1.z, st[(14 - kk) & 7], nb);
          nb = fma((double)c1.w, st[(15 - kk) & 7], nb);
          st[(7 - kk) & 7] = nb;
          long long bits = __double_as_longlong(nb);
          int e2 = (int)((bits >> 52) & 0x7ff) - 1023;
          double mant = __longlong_as_double((bits & 0xFFFFFFFFFFFFFLL) | 0x3FF0000000000000LL);
          float lg = log2f((float)mant);
          bL[t] = (float)(((double)e2 + eacc + (double)lg) * LN2D);
        }
      }
    }
  }
}

// K4: dense output. (R7 verbatim)
__global__ void k_out(const PK* __restrict__ pk, const unsigned long long* __restrict__ w64,
                      const float* __restrict__ aL, const float* __restrict__ bL,
                      float* __restrict__ out, int T, int V, int tPer) {
  int v = blockIdx.x * blockDim.x + threadIdx.x;
  PK p = pk[v];
  unsigned long long mask = (p.len >= 8) ? ~0ull : ((1ull << (8 * p.len)) - 1ull);
  unsigned long long key = p.key;
  float norm = aL[T];
  float base = p.logp - norm;
  int t0 = blockIdx.y * tPer;
  for (int t = t0; t < t0 + tPer; ++t) {
    unsigned long long w = w64[t];
    float val = 0.f;
    if (((w ^ key) & mask) == 0ull)
      val = __expf(aL[t] + base + bL[t + p.len]);
    out[(size_t)t * V + v] = val;
  }
}

extern "C" void kernel_launch(void* const* d_in, const int* in_sizes, int n_in,
                              void* d_out, int out_size, void* d_ws, size_t ws_size,
                              hipStream_t stream) {
  const int* seq    = (const int*)d_in[0];
  const int* pieces = (const int*)d_in[1];
  const int* plens  = (const int*)d_in[2];
  const float* logp = (const float*)d_in[3];
  float* out = (float*)d_out;
  const int T = in_sizes[0];
  const int V = in_sizes[2];

  char* p = (char*)d_ws;
  PK* pk = (PK*)p;                                   p += (size_t)V * sizeof(PK);
  unsigned long long* w64 = (unsigned long long*)p;  p += (size_t)T * 8;
  float* M = (float*)p;                              p += (size_t)T * LMAX * 4;
  float* Wt = (float*)p;                             p += (size_t)128 * 64 * 4;
  int* EWc = (int*)p;                                p += (size_t)128 * 8 * 4;
  float* Pm = (float*)p;                             p += (size_t)128 * 64 * 4;
  float* aL = (float*)p;                             p += 8208;
  float* bL = (float*)p;                             p += 8208;

  int prepN = V + T + T * LMAX;
  k_prep<<<(prepN + 255) / 256, 256, 0, stream>>>(seq, pieces, plens, logp, pk, w64, M, T, V);

  const int tPer2 = 128;
  dim3 g2(V / 256, T / tPer2);
  k_match<<<g2, 256, 0, stream>>>(pk, w64, M, T, V, tPer2);

  k_chunks<<<16, 64, 0, stream>>>(M, Wt, EWc);
  k_fin<<<1, 128, 0, stream>>>(M, Wt, EWc, Pm, aL, bL);

  const int tPer5 = 32;
  dim3 g5(V / 256, T / tPer5);
  k_out<<<g5, 256, 0, stream>>>(pk, w64, aL, bL, out, T, V, tPer5);
}